// Round 8
// baseline (67.828 us; speedup 1.0000x reference)
//
#include <hip/hip_runtime.h>
#include <hip/hip_fp16.h>
#include <math.h>

// (B,Tq,Tk,U) = (32,1024,1024,256), f32 in/out.
// ROUND 8 = ATTRIBUTION ROUND: kernels byte-identical to round 7, but
// sk_mfma_kernel is launched TWICE (idempotent). With r7: T_sk+T_k2 = 43.2us,
// this round: 2*T_sk+T_k2  =>  T_sk = dur_us(r8) - 43.2.
#define NB 32
#define TQ 1024
#define TK 1024
#define UD 256

typedef __attribute__((ext_vector_type(8))) _Float16 f16x8;
typedef __attribute__((ext_vector_type(4))) float f32x4;

__device__ __forceinline__ float fast_tanh(float x) {
  const float e = __expf(2.0f * x);
  return 1.0f - 2.0f / (e + 1.0f);
}

__device__ __forceinline__ f16x8 cvt2(const float4 a, const float4 b) {
  f16x8 h;
  h[0] = (_Float16)a.x; h[1] = (_Float16)a.y;
  h[2] = (_Float16)a.z; h[3] = (_Float16)a.w;
  h[4] = (_Float16)b.x; h[5] = (_Float16)b.y;
  h[6] = (_Float16)b.z; h[7] = (_Float16)b.w;
  return h;
}

// ---------------------------------------------------------------------------
// K1: sk[r] = sum_u v[u] * tanh( sum_c key[r,c] * Wq[u,c] )   (MFMA f16)
// (identical to round 7)
// ---------------------------------------------------------------------------
__global__ __launch_bounds__(512, 4) void sk_mfma_kernel(
    const float* __restrict__ key, const float* __restrict__ Wq,
    const float* __restrict__ v, float* __restrict__ sk) {
  __shared__ _Float16 Bt[8 * 256 * 8];  // 32 KB [ks][u][8]
  __shared__ _Float16 At[8 * 64 * 8];   // 8 KB  [ks][r][8]

  const int tid = threadIdx.x;
  const int lane = tid & 63;
  const int wid = tid >> 6;  // 0..7
  const int wr = wid >> 2;   // 0..1 (row half)
  const int wc = wid & 3;    // 0..3 (u quarter)
  const int lx = lane & 15;
  const int lg = lane >> 4;
  const int row0 = blockIdx.x * 64;

  const int ar = tid & 63, ah = tid >> 6;   // A: row, k-slot
  const int bu = tid & 255, bg = tid >> 8;  // B: u row, ks half

  f32x4 acc[2][4];
#pragma unroll
  for (int m = 0; m < 2; ++m)
#pragma unroll
    for (int n = 0; n < 4; ++n) acc[m][n] = (f32x4){0.f, 0.f, 0.f, 0.f};

  for (int p = 0; p < 4; ++p) {
    const int k0 = p * 64;
    {
      const float* ga = key + (size_t)(row0 + ar) * UD + k0 + ah * 8;
      const float4 a0 = *reinterpret_cast<const float4*>(ga);
      const float4 a1 = *reinterpret_cast<const float4*>(ga + 4);
      *reinterpret_cast<f16x8*>(At + ((ah << 6) + ar) * 8) = cvt2(a0, a1);
    }
    {
      const float* gb = Wq + (size_t)bu * UD + k0 + bg * 32;
#pragma unroll
      for (int gg = 0; gg < 4; ++gg) {
        const float4 b0 = *reinterpret_cast<const float4*>(gb + gg * 8);
        const float4 b1 = *reinterpret_cast<const float4*>(gb + gg * 8 + 4);
        const int ks = bg * 4 + gg;
        *reinterpret_cast<f16x8*>(Bt + ((ks << 8) + bu) * 8) = cvt2(b0, b1);
      }
    }
    __syncthreads();

#pragma unroll
    for (int kc = 0; kc < 2; ++kc) {
      const int ks = kc * 4 + lg;
      f16x8 af[2], bf[4];
#pragma unroll
      for (int m = 0; m < 2; ++m)
        af[m] = *reinterpret_cast<const f16x8*>(
            At + ((ks << 6) + wr * 32 + m * 16 + lx) * 8);
#pragma unroll
      for (int n = 0; n < 4; ++n)
        bf[n] = *reinterpret_cast<const f16x8*>(
            Bt + ((ks << 8) + wc * 64 + n * 16 + lx) * 8);
#pragma unroll
      for (int m = 0; m < 2; ++m)
#pragma unroll
        for (int n = 0; n < 4; ++n)
          acc[m][n] = __builtin_amdgcn_mfma_f32_16x16x32_f16(
              af[m], bf[n], acc[m][n], 0, 0, 0);
    }
    __syncthreads();
  }

  float vv[4];
#pragma unroll
  for (int n = 0; n < 4; ++n) vv[n] = v[wc * 64 + n * 16 + lx];

  float* red = (float*)At;
  float part[2][4];
#pragma unroll
  for (int m = 0; m < 2; ++m)
#pragma unroll
    for (int r = 0; r < 4; ++r) part[m][r] = 0.f;
#pragma unroll
  for (int m = 0; m < 2; ++m)
#pragma unroll
    for (int n = 0; n < 4; ++n)
#pragma unroll
      for (int r = 0; r < 4; ++r)
        part[m][r] += vv[n] * fast_tanh(acc[m][n][r]);

#pragma unroll
  for (int m = 0; m < 2; ++m)
#pragma unroll
    for (int r = 0; r < 4; ++r) {
      float s = part[m][r];
      s += __shfl_xor(s, 1);
      s += __shfl_xor(s, 2);
      s += __shfl_xor(s, 4);
      s += __shfl_xor(s, 8);
      if (lx == 0) red[(wr * 32 + m * 16 + lg * 4 + r) * 4 + wc] = s;
    }
  __syncthreads();
  if (tid < 64) {
    sk[row0 + tid] = red[tid * 4 + 0] + red[tid * 4 + 1] + red[tid * 4 + 2] +
                     red[tid * 4 + 3];
  }
}

// ---------------------------------------------------------------------------
// K2: fused softmax + PV + broadcast, split over d. (identical to round 7)
// ---------------------------------------------------------------------------
__global__ __launch_bounds__(1024) void pv_bcast_kernel(
    const float* __restrict__ sk, const int* __restrict__ vlen,
    const float* __restrict__ value, float* __restrict__ out) {
  const int b = blockIdx.x >> 3;
  const int dc = blockIdx.x & 7;
  const int tid = threadIdx.x;
  const int wid = tid >> 6;
  const int vl = vlen[b];
  __shared__ float wbuf[1024];
  __shared__ float redm[16];
  __shared__ float redz[16];
  __shared__ float racc[128][36];
  __shared__ float fin2[8][32];
  __shared__ float fin[32];
  const float* skb = sk + b * TK;

  if (vl == 0) {
    wbuf[tid] = 1.0f / (float)TK;
  } else {
    const float s = skb[tid];
    const bool val = tid < vl;
    float m = val ? s : -1e30f;
    for (int off = 1; off < 64; off <<= 1) m = fmaxf(m, __shfl_xor(m, off));
    if ((tid & 63) == 0) redm[wid] = m;
    __syncthreads();
    m = redm[0];
#pragma unroll
    for (int w = 1; w < 16; ++w) m = fmaxf(m, redm[w]);
    const float e = val ? __expf(s - m) : 0.f;
    float zs = e;
    for (int off = 1; off < 64; off <<= 1) zs += __shfl_xor(zs, off);
    if ((tid & 63) == 0) redz[wid] = zs;
    __syncthreads();
    zs = redz[0];
#pragma unroll
    for (int w = 1; w < 16; ++w) zs += redz[w];
    wbuf[tid] = e * (1.0f / zs);
  }
  __syncthreads();

  const int c = tid & 7;
  const int kg = tid >> 3;
  const float* vb = value + (size_t)b * TK * UD + dc * 32 + c * 4;
  float4 a = make_float4(0.f, 0.f, 0.f, 0.f);
#pragma unroll
  for (int i = 0; i < 8; ++i) {
    const int k = i * 128 + kg;
    const float wk = wbuf[k];
    const float4 x = *reinterpret_cast<const float4*>(vb + (size_t)k * UD);
    a.x = fmaf(wk, x.x, a.x);
    a.y = fmaf(wk, x.y, a.y);
    a.z = fmaf(wk, x.z, a.z);
    a.w = fmaf(wk, x.w, a.w);
  }
  *reinterpret_cast<float4*>(&racc[kg][c * 4]) = a;
  __syncthreads();
  if (tid < 256) {
    const int d = tid & 31;
    const int g = tid >> 5;
    float s = 0.f;
#pragma unroll
    for (int j = 0; j < 16; ++j) s += racc[g * 16 + j][d];
    fin2[g][d] = s;
  }
  __syncthreads();
  if (tid < 32) {
    float s = 0.f;
#pragma unroll
    for (int g = 0; g < 8; ++g) s += fin2[g][tid];
    fin[tid] = s;
  }
  __syncthreads();

  const float4 f4 = *reinterpret_cast<const float4*>(&fin[c * 4]);
  float* ob = out + (size_t)b * TQ * UD + dc * 32 + c * 4;
#pragma unroll
  for (int i = 0; i < 8; ++i) {
    const int q = i * 128 + kg;
    *reinterpret_cast<float4*>(ob + (size_t)q * UD) = f4;
  }
}

// ---------------------------------------------------------------------------
extern "C" void kernel_launch(void* const* d_in, const int* in_sizes, int n_in,
                              void* d_out, int out_size, void* d_ws,
                              size_t ws_size, hipStream_t stream) {
  // inputs: 0 query, 1 key, 2 value, 3 valid_length, 4 W_k, 5 W_q, 6 v
  const float* key = (const float*)d_in[1];
  const float* value = (const float*)d_in[2];
  const int* vlen = (const int*)d_in[3];
  const float* Wq = (const float*)d_in[5];
  const float* v = (const float*)d_in[6];
  float* out = (float*)d_out;

  float* sk = (float*)d_ws;  // 32768 f32 = 128 KB

  // Attribution: sk launched twice (idempotent). dur_us = 2*T_sk + T_k2.
  sk_mfma_kernel<<<(NB * TK) / 64, 512, 0, stream>>>(key, Wq, v, sk);
  sk_mfma_kernel<<<(NB * TK) / 64, 512, 0, stream>>>(key, Wq, v, sk);
  pv_bcast_kernel<<<NB * 8, 1024, 0, stream>>>(sk, vlen, value, out);
}

// Round 9
// 49.905 us; speedup vs baseline: 1.3591x; 1.3591x over previous
//
#include <hip/hip_runtime.h>
#include <hip/hip_fp16.h>
#include <math.h>

// (B,Tq,Tk,U) = (32,1024,1024,256), f32 in/out.
#define NB 32
#define TQ 1024
#define TK 1024
#define UD 256

typedef __attribute__((ext_vector_type(8))) _Float16 f16x8;
typedef __attribute__((ext_vector_type(4))) _Float16 f16x4;
typedef __attribute__((ext_vector_type(4))) float f32x4;

__device__ __forceinline__ float fast_tanh(float x) {
  const float e = __expf(2.0f * x);
  return 1.0f - 2.0f / (e + 1.0f);
}

// ---------------------------------------------------------------------------
// K0: Wq f32 -> f16, k-slot-major: wq16t[ks][u][8] (ks = k>>3). Coalesced
// reads (32 lanes span one 1 KB row); scattered 16-B writes (tiny, L2).
// ---------------------------------------------------------------------------
__global__ __launch_bounds__(256) void cvt_wq_kernel(
    const float* __restrict__ Wq, _Float16* __restrict__ wq16t) {
  const int idx = blockIdx.x * 256 + threadIdx.x;  // 8192
  const int u = idx >> 5;
  const int ks = idx & 31;
  const float4 w0 = *reinterpret_cast<const float4*>(Wq + u * UD + ks * 8);
  const float4 w1 = *reinterpret_cast<const float4*>(Wq + u * UD + ks * 8 + 4);
  f16x8 h;
  h[0] = (_Float16)w0.x; h[1] = (_Float16)w0.y;
  h[2] = (_Float16)w0.z; h[3] = (_Float16)w0.w;
  h[4] = (_Float16)w1.x; h[5] = (_Float16)w1.y;
  h[6] = (_Float16)w1.z; h[7] = (_Float16)w1.w;
  *reinterpret_cast<f16x8*>(wq16t + ((size_t)ks * 256 + u) * 8) = h;
}

// ---------------------------------------------------------------------------
// K1: sk[r] = sum_u v[u] * tanh( sum_c key[r,c] * Wq[u,c] )   (MFMA f16)
// 512 blocks x 512 thr (8 waves, 2M x 4N). 64 rows x 256 u per block.
// ALL global loads wave-contiguous:
//   A: one 1 KB key row per wave-load, cvt in reg, XOR-swizzled LDS
//      At[ks][row ^ (ks&7)][8]  (32 KB, staged once).
//   B: linear 16 KB copies of pre-converted k-slot-major wq16t into
//      double-buffered Bt[2][4 ks][256 u][8]  (2x16 KB), 1 barrier/phase.
// 8 phases x (2 af + 4 bf ds_read_b128 + 8 MFMA)/wave.
// ---------------------------------------------------------------------------
__global__ __launch_bounds__(512, 4) void sk_mfma_kernel(
    const float* __restrict__ key, const _Float16* __restrict__ wq16t,
    const float* __restrict__ v, float* __restrict__ sk) {
  __shared__ _Float16 At[32 * 64 * 8];     // 32 KB
  __shared__ _Float16 Bt[2][4 * 256 * 8];  // 2 x 16 KB

  const int tid = threadIdx.x;
  const int lane = tid & 63;
  const int wid = tid >> 6;  // 0..7
  const int wr = wid >> 2;   // 0..1 (row half)
  const int wc = wid & 3;    // 0..3 (u quarter)
  const int lx = lane & 15;
  const int lg = lane >> 4;
  const int row0 = blockIdx.x * 64;

  // ---- stage A once: wave wid loads rows wid*8..+7, 1 KB contiguous each ----
  {
    const int ks = lane >> 1;  // 0..31
    const int jh = lane & 1;   // 16-B half
#pragma unroll
    for (int i = 0; i < 8; ++i) {
      const int r = wid * 8 + i;
      const float4 a = *reinterpret_cast<const float4*>(
          key + (size_t)(row0 + r) * UD + lane * 4);
      f16x4 h;
      h[0] = (_Float16)a.x; h[1] = (_Float16)a.y;
      h[2] = (_Float16)a.z; h[3] = (_Float16)a.w;
      const int rs = r ^ (ks & 7);
      *reinterpret_cast<f16x4*>(At + ((ks * 64 + rs) * 8 + jh * 4)) = h;
    }
  }

  // ---- stage B phase 0 (linear 16 KB copy) ----
#pragma unroll
  for (int it = 0; it < 2; ++it) {
    const int f = tid + it * 512;
    *(reinterpret_cast<f16x8*>(Bt[0]) + f) =
        *(reinterpret_cast<const f16x8*>(wq16t) + f);
  }
  __syncthreads();

  f32x4 acc[2][4];
#pragma unroll
  for (int m = 0; m < 2; ++m)
#pragma unroll
    for (int n = 0; n < 4; ++n) acc[m][n] = (f32x4){0.f, 0.f, 0.f, 0.f};

#pragma unroll
  for (int p = 0; p < 8; ++p) {
    const int cur = p & 1;
    if (p < 7) {  // stage next phase into the other buffer
#pragma unroll
      for (int it = 0; it < 2; ++it) {
        const int f = tid + it * 512;
        *(reinterpret_cast<f16x8*>(Bt[cur ^ 1]) + f) =
            *(reinterpret_cast<const f16x8*>(wq16t + (size_t)(p + 1) * 8192) +
              f);
      }
    }
    // compute phase p: ks_global = p*4 + lg
    const int ksg = p * 4 + lg;
    f16x8 af[2], bf[4];
#pragma unroll
    for (int m = 0; m < 2; ++m) {
      const int row = wr * 32 + m * 16 + lx;
      const int rs = row ^ (ksg & 7);
      af[m] = *reinterpret_cast<const f16x8*>(At + (ksg * 64 + rs) * 8);
    }
#pragma unroll
    for (int n = 0; n < 4; ++n) {
      const int u = wc * 64 + n * 16 + lx;
      bf[n] = *reinterpret_cast<const f16x8*>(Bt[cur] + (lg * 256 + u) * 8);
    }
#pragma unroll
    for (int m = 0; m < 2; ++m)
#pragma unroll
      for (int n = 0; n < 4; ++n)
        acc[m][n] = __builtin_amdgcn_mfma_f32_16x16x32_f16(af[m], bf[n],
                                                           acc[m][n], 0, 0, 0);
    __syncthreads();
  }

  // ---- epilogue: tanh, dot v, shfl-reduce over lx, LDS-reduce over wc ----
  // acc[m][n] reg r: row = wr*32 + m*16 + lg*4 + r ; u = wc*64 + n*16 + lx
  float vv[4];
#pragma unroll
  for (int n = 0; n < 4; ++n) vv[n] = v[wc * 64 + n * 16 + lx];

  float* red = (float*)At;  // At free after final barrier
  float part[2][4];
#pragma unroll
  for (int m = 0; m < 2; ++m)
#pragma unroll
    for (int r = 0; r < 4; ++r) part[m][r] = 0.f;
#pragma unroll
  for (int m = 0; m < 2; ++m)
#pragma unroll
    for (int n = 0; n < 4; ++n)
#pragma unroll
      for (int r = 0; r < 4; ++r)
        part[m][r] += vv[n] * fast_tanh(acc[m][n][r]);

#pragma unroll
  for (int m = 0; m < 2; ++m)
#pragma unroll
    for (int r = 0; r < 4; ++r) {
      float s = part[m][r];
      s += __shfl_xor(s, 1);
      s += __shfl_xor(s, 2);
      s += __shfl_xor(s, 4);
      s += __shfl_xor(s, 8);
      if (lx == 0) red[(wr * 32 + m * 16 + lg * 4 + r) * 4 + wc] = s;
    }
  __syncthreads();
  if (tid < 64) {
    sk[row0 + tid] = red[tid * 4 + 0] + red[tid * 4 + 1] + red[tid * 4 + 2] +
                     red[tid * 4 + 3];
  }
}

// ---------------------------------------------------------------------------
// K2: fused softmax + PV partial (r1-proven contiguous pattern).
// Block (b,ch): softmax stats from sk (4 KB L2-hot), then
// part[b][ch][d=tid] = sum_{k in 64-chunk} w[k]*value[b,k,d].
// Wave reads 256 B contiguous per k-row; block covers the full 1 KB row.
// ---------------------------------------------------------------------------
__global__ __launch_bounds__(256) void pv_kernel(
    const float* __restrict__ sk, const int* __restrict__ vlen,
    const float* __restrict__ value, float* __restrict__ part) {
  const int b = blockIdx.x >> 4;
  const int ch = blockIdx.x & 15;
  const int tid = threadIdx.x;
  const int vl = vlen[b];
  __shared__ float wbuf[64];
  __shared__ float red4[8];
  const float* skb = sk + b * TK;

  if (vl == 0) {  // uniform softmax over the constant-fill row
    if (tid < 64) wbuf[tid] = 1.0f / (float)TK;
  } else {
    float m = -1e30f;
#pragma unroll
    for (int idx = 0; idx < 4; ++idx) {
      const int k = tid + idx * 256;
      if (k < vl) m = fmaxf(m, skb[k]);
    }
    for (int off = 1; off < 64; off <<= 1) m = fmaxf(m, __shfl_xor(m, off));
    if ((tid & 63) == 0) red4[tid >> 6] = m;
    __syncthreads();
    m = fmaxf(fmaxf(red4[0], red4[1]), fmaxf(red4[2], red4[3]));
    float zs = 0.f;
#pragma unroll
    for (int idx = 0; idx < 4; ++idx) {
      const int k = tid + idx * 256;
      zs += (k < vl) ? __expf(skb[k] - m) : 0.f;
    }
    for (int off = 1; off < 64; off <<= 1) zs += __shfl_xor(zs, off);
    if ((tid & 63) == 0) red4[4 + (tid >> 6)] = zs;
    __syncthreads();
    const float rz = 1.0f / (red4[4] + red4[5] + red4[6] + red4[7]);
    if (tid < 64) {
      const int k = ch * 64 + tid;
      wbuf[tid] = (k < vl) ? __expf(skb[k] - m) * rz : 0.f;
    }
  }
  __syncthreads();

  const int d = tid;
  const float* vb = value + ((size_t)b * TK + ch * 64) * UD;
  float acc = 0.f;
#pragma unroll 8
  for (int k = 0; k < 64; ++k)
    acc = fmaf(wbuf[k], vb[(size_t)k * UD + d], acc);
  part[(size_t)(b * 16 + ch) * UD + d] = acc;
}

// ---------------------------------------------------------------------------
// K3: reduce 16 partials -> out_row, broadcast over 64 q rows/block (r1's).
// ---------------------------------------------------------------------------
__global__ __launch_bounds__(256) void bcast_kernel(
    const float* __restrict__ part, float* __restrict__ out) {
  const int b = blockIdx.x >> 4;
  const int qc = blockIdx.x & 15;
  const int tid = threadIdx.x;
  const int qoff = tid >> 6;      // 0..3
  const int dd = (tid & 63) * 4;  // 0..252

  float4 s = make_float4(0.f, 0.f, 0.f, 0.f);
#pragma unroll
  for (int c = 0; c < 16; ++c) {
    const float4 p = *reinterpret_cast<const float4*>(
        &part[(size_t)(b * 16 + c) * UD + dd]);
    s.x += p.x; s.y += p.y; s.z += p.z; s.w += p.w;
  }

  float* ob = out + (size_t)b * TQ * UD + (size_t)qc * 64 * UD;
#pragma unroll 4
  for (int q4 = 0; q4 < 16; ++q4) {
    *reinterpret_cast<float4*>(&ob[(size_t)(q4 * 4 + qoff) * UD + dd]) = s;
  }
}

// ---------------------------------------------------------------------------
extern "C" void kernel_launch(void* const* d_in, const int* in_sizes, int n_in,
                              void* d_out, int out_size, void* d_ws,
                              size_t ws_size, hipStream_t stream) {
  // inputs: 0 query, 1 key, 2 value, 3 valid_length, 4 W_k, 5 W_q, 6 v
  const float* key = (const float*)d_in[1];
  const float* value = (const float*)d_in[2];
  const int* vlen = (const int*)d_in[3];
  const float* Wq = (const float*)d_in[5];
  const float* v = (const float*)d_in[6];
  float* out = (float*)d_out;

  char* ws = (char*)d_ws;
  _Float16* wq16t = (_Float16*)(ws);    // 128 KB (k-slot-major f16 Wq)
  float* sk = (float*)(ws + 131072);    // 128 KB
  float* part = (float*)(ws + 262144);  // 512 KB

  cvt_wq_kernel<<<32, 256, 0, stream>>>(Wq, wq16t);
  sk_mfma_kernel<<<(NB * TK) / 64, 512, 0, stream>>>(key, wq16t, v, sk);
  pv_kernel<<<NB * 16, 256, 0, stream>>>(sk, vlen, value, part);
  bcast_kernel<<<NB * 16, 256, 0, stream>>>(part, out);
}